// Round 9
// baseline (699.761 us; speedup 1.0000x reference)
//
#include <hip/hip_runtime.h>

#define N_NODES 100000
#define N_EDGES 3200000
#define NGRAPH 512
#define NCLASS 6
#define BN_EPS 1e-5f

#define BSHIFT 8
#define NBUCK 391          // ceil(100000 / 256)
#define CHUNK 8192         // edges per block in bucket passes
#define EB 391             // ceil(N_EDGES / CHUNK)
#define NBLK_NODE 391      // ceil(N_NODES / 256)
#define MLPG 1563          // ceil(N_NODES / 64) = k_layer grid = #partials rows
#define CAST_B 6250        // N_NODES*64/4/256 exactly

typedef unsigned short u16;
typedef unsigned int u32;
typedef __attribute__((ext_vector_type(8))) short bf16x8;
typedef __attribute__((ext_vector_type(4))) float f32x4;

__device__ __forceinline__ float bflo(u32 b) {
    u32 t = b << 16; return __builtin_bit_cast(float, t);
}
__device__ __forceinline__ float bfhi(u32 b) {
    u32 t = b & 0xffff0000u; return __builtin_bit_cast(float, t);
}
__device__ __forceinline__ u16 f2bf(float f) {   // round-to-nearest-even
    u32 u = __builtin_bit_cast(u32, f);
    return (u16)((u + 0x7fffu + ((u >> 16) & 1u)) >> 16);
}

// ---------------- fused setup: cast | weight-prep+ss0 | edge hist | gstart ----------------
__global__ void k_setup(const float* __restrict__ x, u16* __restrict__ xb,
                        const float* __restrict__ W10, const float* __restrict__ W20,
                        const float* __restrict__ W11, const float* __restrict__ W21,
                        const float* __restrict__ W12, const float* __restrict__ W22,
                        u16* __restrict__ Wtg, float* __restrict__ ss0,
                        const int* __restrict__ dst, const int* __restrict__ batch,
                        int* __restrict__ blockhist, int* __restrict__ gstart) {
    __shared__ int hist[NBUCK];
    int b = blockIdx.x;
    int t = threadIdx.x;
    if (b < CAST_B) {
        int base = (b * 256 + t) * 4;
        float4 v = *(const float4*)(x + base);
        ushort4 o = make_ushort4(f2bf(v.x), f2bf(v.y), f2bf(v.z), f2bf(v.w));
        *(ushort4*)(xb + base) = o;
    } else if (b < CAST_B + 97) {
        int bb = b - CAST_B;
        if (bb < 96) {
            int e = bb * 256 + t;          // < 24576 = 6 * 4096
            int mat = e >> 12;
            int i = e & 4095;
            const float* s = (mat == 0) ? W10 : (mat == 1) ? W20 : (mat == 2) ? W11
                           : (mat == 3) ? W21 : (mat == 4) ? W12 : W22;
            float v = s[i];
            int k = i >> 6, c = i & 63;
            Wtg[mat * 4608 + c * 72 + k] = f2bf(v);
        } else {
            if (t < 64) ss0[t] = 1.0f;
            else if (t < 128) ss0[t] = 0.0f;
        }
    } else if (b < CAST_B + 97 + EB) {
        int be = b - (CAST_B + 97);
        long e0 = (long)be * CHUNK;
        for (int i = t; i < NBUCK; i += 256) hist[i] = 0;
        __syncthreads();
        for (int i = t; i < CHUNK; i += 256) {
            long e = e0 + i;
            if (e < N_EDGES) atomicAdd(&hist[dst[e] >> BSHIFT], 1);
        }
        __syncthreads();
        for (int i = t; i < NBUCK; i += 256) blockhist[be * NBUCK + i] = hist[i];
    } else {
        int i = (b - (CAST_B + 97 + EB)) * 256 + t;
        if (i < N_NODES) {
            int bi = batch[i];
            int bp = (i == 0) ? -1 : batch[i - 1];
            for (int g = bp + 1; g <= bi; ++g) gstart[g] = i;
            if (i == N_NODES - 1)
                for (int g = bi + 1; g <= NGRAPH; ++g) gstart[g] = N_NODES;
        }
    }
}

// ---------------- CSR build (unchanged) ----------------

__global__ void k_scan_cols(int* __restrict__ blockhist, int* __restrict__ colsum) {
    __shared__ int sh[512];
    int k = blockIdx.x;
    int t = threadIdx.x;
    int v = (t < EB) ? blockhist[t * NBUCK + k] : 0;
    sh[t] = v;
    __syncthreads();
    for (int off = 1; off < 512; off <<= 1) {
        int x = (t >= off) ? sh[t - off] : 0;
        __syncthreads();
        sh[t] += x;
        __syncthreads();
    }
    if (t < EB) blockhist[t * NBUCK + k] = sh[t] - v;
    if (t == 511) colsum[k] = sh[511];
}

__global__ void k_scan_b(const int* __restrict__ colsum, int* __restrict__ bstart,
                         int* __restrict__ rowstart) {
    __shared__ int sh[512];
    int t = threadIdx.x;
    int v = (t < NBUCK) ? colsum[t] : 0;
    sh[t] = v;
    __syncthreads();
    for (int off = 1; off < 512; off <<= 1) {
        int x = (t >= off) ? sh[t - off] : 0;
        __syncthreads();
        sh[t] += x;
        __syncthreads();
    }
    if (t < NBUCK) bstart[t] = sh[t] - v;
    if (t == NBUCK - 1) bstart[NBUCK] = sh[t];
    if (t == 0) rowstart[N_NODES] = N_EDGES;
}

__global__ void k_bscatter(const int* __restrict__ src, const int* __restrict__ dst,
                           const int* __restrict__ bstart,
                           const int* __restrict__ blockhist, int* __restrict__ pairs) {
    __shared__ int base[NBUCK];
    __shared__ int hist[NBUCK];
    int tid = threadIdx.x;
    int b = blockIdx.x;
    long e0 = (long)b * CHUNK;
    for (int k = tid; k < NBUCK; k += 256) {
        base[k] = bstart[k] + blockhist[b * NBUCK + k];
        hist[k] = 0;
    }
    __syncthreads();
    for (int i = tid; i < CHUNK; i += 256) {
        long e = e0 + i;
        if (e < N_EDGES) {
            int d = dst[e];
            int k = d >> BSHIFT;
            int r = atomicAdd(&hist[k], 1);
            pairs[base[k] + r] = (src[e] << 8) | (d & 255);
        }
    }
}

__global__ void k_bsort(const int* __restrict__ pairs, const int* __restrict__ bstart,
                        int* __restrict__ rowstart, int* __restrict__ esrc) {
    __shared__ int deg[256];
    __shared__ int cur[256];
    int b = blockIdx.x;
    int tid = threadIdx.x;
    int p0 = bstart[b], p1 = bstart[b + 1];
    deg[tid] = 0;
    __syncthreads();
    for (int i = p0 + tid; i < p1; i += 256)
        atomicAdd(&deg[pairs[i] & 255], 1);
    __syncthreads();
    int v = deg[tid];
    cur[tid] = v;
    __syncthreads();
    for (int off = 1; off < 256; off <<= 1) {
        int x = (tid >= off) ? cur[tid - off] : 0;
        __syncthreads();
        cur[tid] += x;
        __syncthreads();
    }
    int excl = cur[tid] - v;
    int node = (b << BSHIFT) + tid;
    if (node < N_NODES) rowstart[node] = p0 + excl;
    __syncthreads();
    cur[tid] = excl;
    __syncthreads();
    for (int i = p0 + tid; i < p1; i += 256) {
        u32 pr = (u32)pairs[i];
        int r = atomicAdd(&cur[pr & 255], 1);
        esrc[p0 + r] = (int)(pr >> 8);
    }
}

// ---------------- BN fold: reduce partials -> scale/shift ----------------
__global__ void k_bn(const float* __restrict__ partials, const float* __restrict__ g,
                     const float* __restrict__ be, float* __restrict__ ss) {
    __shared__ float sS[256];
    __shared__ float sQ[256];
    int f = blockIdx.x;
    int t = threadIdx.x;
    float aS = 0.f, aQ = 0.f;
    for (int b = t; b < MLPG; b += 256) {
        aS += partials[b * 128 + f];
        aQ += partials[b * 128 + 64 + f];
    }
    sS[t] = aS; sQ[t] = aQ;
    __syncthreads();
    for (int off = 128; off >= 1; off >>= 1) {
        if (t < off) { sS[t] += sS[t + off]; sQ[t] += sQ[t + off]; }
        __syncthreads();
    }
    if (t == 0) {
        float mu = sS[0] / (float)N_NODES;
        float var = fmaxf(sQ[0] / (float)N_NODES - mu * mu, 0.f);
        float sc = g[f] * rsqrtf(var + BN_EPS);
        ss[f] = sc;
        ss[64 + f] = be[f] - mu * sc;
    }
}

// ---------------- fused GIN layer: agg (R8 loop) -> LDS -> MFMA MLP ----------------
// Phase A: wave w aggregates nodes r0+w*16+[0,16) sequentially (R8 gather shape:
// 8 rows per dwordx4, all-lanes-active clamped shfls), quantizes to bf16 in LDS.
// Phase B: R7 MFMA MLP with A-frags from LDS; B-frags (weights) straight from
// global/L2 (18KB hot everywhere) — keeps LDS at ~19KB -> 8 blocks/CU.
// C written to a DIFFERENT buffer than hin (other blocks still gather from hin).
__global__ __launch_bounds__(256) void k_layer(
    const u16* __restrict__ hin, const float* __restrict__ ss,
    const float* __restrict__ epsp, const int* __restrict__ rowstart,
    const int* __restrict__ esrc, const u16* __restrict__ Wt,
    const float* __restrict__ b1, const float* __restrict__ b2,
    u16* __restrict__ C, float* __restrict__ partials) {
    __shared__ __align__(16) u16 Ain[64 * 72];
    __shared__ __align__(16) u16 Hs[64 * 72];
    __shared__ float ssum[64];
    __shared__ float ssq[64];
    int tid = threadIdx.x;
    int lane = tid & 63;
    int w = tid >> 6;
    int r0 = blockIdx.x * 64;
    if (tid < 64) { ssum[tid] = 0.f; ssq[tid] = 0.f; }

    // ---- phase A ----
    int grp = lane >> 3;
    int f0 = 8 * (lane & 7);
    float epsv = 1.0f + epsp[0];
    float4 scA = *(const float4*)(ss + f0);
    float4 scB = *(const float4*)(ss + f0 + 4);
    float4 shA = *(const float4*)(ss + 64 + f0);
    float4 shB = *(const float4*)(ss + 64 + f0 + 4);
    float sc[8] = {scA.x, scA.y, scA.z, scA.w, scB.x, scB.y, scB.z, scB.w};
    float sh[8] = {shA.x, shA.y, shA.z, shA.w, shB.x, shB.y, shB.z, shB.w};

    for (int t = 0; t < 16; ++t) {
        int node = r0 + w * 16 + t;
        int rowl = w * 16 + t;
        if (node < N_NODES) {
            float acc[8] = {0.f, 0.f, 0.f, 0.f, 0.f, 0.f, 0.f, 0.f};
            int e0 = rowstart[node], e1 = rowstart[node + 1];
            for (int i = e0; i < e1; i += 64) {
                int cnt = min(e1 - i, 64);
                int src = (lane < cnt) ? esrc[i + lane] : 0;
                int j = 0;
                for (; j + 16 <= cnt; j += 16) {
                    int a = __shfl(src, j + grp);
                    int b = __shfl(src, j + 8 + grp);
                    uint4 va = *(const uint4*)(hin + (size_t)a * 64 + f0);
                    uint4 vb = *(const uint4*)(hin + (size_t)b * 64 + f0);
                    acc[0] += bflo(va.x); acc[1] += bfhi(va.x);
                    acc[2] += bflo(va.y); acc[3] += bfhi(va.y);
                    acc[4] += bflo(va.z); acc[5] += bfhi(va.z);
                    acc[6] += bflo(va.w); acc[7] += bfhi(va.w);
                    acc[0] += bflo(vb.x); acc[1] += bfhi(vb.x);
                    acc[2] += bflo(vb.y); acc[3] += bfhi(vb.y);
                    acc[4] += bflo(vb.z); acc[5] += bfhi(vb.z);
                    acc[6] += bflo(vb.w); acc[7] += bfhi(vb.w);
                }
                if (j + 8 <= cnt) {
                    int a = __shfl(src, j + grp);
                    uint4 va = *(const uint4*)(hin + (size_t)a * 64 + f0);
                    acc[0] += bflo(va.x); acc[1] += bfhi(va.x);
                    acc[2] += bflo(va.y); acc[3] += bfhi(va.y);
                    acc[4] += bflo(va.z); acc[5] += bfhi(va.z);
                    acc[6] += bflo(va.w); acc[7] += bfhi(va.w);
                    j += 8;
                }
                if (j < cnt) {   // clamp src (all lanes active), gate accumulate
                    int jj = j + grp;
                    int a = __shfl(src, (jj < cnt) ? jj : (cnt - 1));
                    uint4 va = *(const uint4*)(hin + (size_t)a * 64 + f0);
                    if (jj < cnt) {
                        acc[0] += bflo(va.x); acc[1] += bfhi(va.x);
                        acc[2] += bflo(va.y); acc[3] += bfhi(va.y);
                        acc[4] += bflo(va.z); acc[5] += bfhi(va.z);
                        acc[6] += bflo(va.w); acc[7] += bfhi(va.w);
                    }
                }
            }
            #pragma unroll
            for (int k = 0; k < 8; ++k) {
                acc[k] += __shfl_xor(acc[k], 8);
                acc[k] += __shfl_xor(acc[k], 16);
                acc[k] += __shfl_xor(acc[k], 32);
            }
            float deg = (float)(e1 - e0);
            uint4 sb = *(const uint4*)(hin + (size_t)node * 64 + f0);
            float self[8] = {bflo(sb.x), bfhi(sb.x), bflo(sb.y), bfhi(sb.y),
                             bflo(sb.z), bfhi(sb.z), bflo(sb.w), bfhi(sb.w)};
            if (grp == 0) {
                u32 pk[4];
                #pragma unroll
                for (int k = 0; k < 4; ++k) {
                    float oa = sc[2 * k] * (acc[2 * k] + epsv * self[2 * k]) +
                               (deg + epsv) * sh[2 * k];
                    float ob = sc[2 * k + 1] * (acc[2 * k + 1] + epsv * self[2 * k + 1]) +
                               (deg + epsv) * sh[2 * k + 1];
                    pk[k] = (u32)f2bf(oa) | ((u32)f2bf(ob) << 16);
                }
                *(uint4*)((u32*)Ain + rowl * 36 + (lane & 7) * 4) =
                    make_uint4(pk[0], pk[1], pk[2], pk[3]);
            }
        } else if (grp == 0) {
            *(uint4*)((u32*)Ain + rowl * 36 + (lane & 7) * 4) = make_uint4(0, 0, 0, 0);
        }
    }
    __syncthreads();

    // ---- phase B ----
    const u16* Wt2 = Wt + 4608;
    int m = lane & 15;
    int q = lane >> 4;

    bf16x8 a0 = *(const bf16x8*)(&Ain[(w * 16 + m) * 72 + q * 8]);
    bf16x8 a1 = *(const bf16x8*)(&Ain[(w * 16 + m) * 72 + 32 + q * 8]);
    f32x4 acc[4];
    #pragma unroll
    for (int c = 0; c < 4; ++c) {
        acc[c] = (f32x4){0.f, 0.f, 0.f, 0.f};
        bf16x8 bA = *(const bf16x8*)(&Wt[(c * 16 + m) * 72 + q * 8]);
        bf16x8 bB = *(const bf16x8*)(&Wt[(c * 16 + m) * 72 + 32 + q * 8]);
        acc[c] = __builtin_amdgcn_mfma_f32_16x16x32_bf16(a0, bA, acc[c], 0, 0, 0);
        acc[c] = __builtin_amdgcn_mfma_f32_16x16x32_bf16(a1, bB, acc[c], 0, 0, 0);
    }
    #pragma unroll
    for (int c = 0; c < 4; ++c) {
        int col = c * 16 + m;
        float bb = b1[col];
        #pragma unroll
        for (int r = 0; r < 4; ++r) {
            int rl = w * 16 + q * 4 + r;
            Hs[rl * 72 + col] = f2bf(fmaxf(acc[c][r] + bb, 0.f));
        }
    }
    bf16x8 h0 = *(const bf16x8*)(&Hs[(w * 16 + m) * 72 + q * 8]);
    bf16x8 h1 = *(const bf16x8*)(&Hs[(w * 16 + m) * 72 + 32 + q * 8]);
    f32x4 acc2[4];
    #pragma unroll
    for (int c = 0; c < 4; ++c) {
        acc2[c] = (f32x4){0.f, 0.f, 0.f, 0.f};
        bf16x8 bA = *(const bf16x8*)(&Wt2[(c * 16 + m) * 72 + q * 8]);
        bf16x8 bB = *(const bf16x8*)(&Wt2[(c * 16 + m) * 72 + 32 + q * 8]);
        acc2[c] = __builtin_amdgcn_mfma_f32_16x16x32_bf16(h0, bA, acc2[c], 0, 0, 0);
        acc2[c] = __builtin_amdgcn_mfma_f32_16x16x32_bf16(h1, bB, acc2[c], 0, 0, 0);
    }
    #pragma unroll
    for (int c = 0; c < 4; ++c) {
        int col = c * 16 + m;
        float bb = b2[col];
        float psum = 0.f, psq = 0.f;
        #pragma unroll
        for (int r = 0; r < 4; ++r) {
            int rg = r0 + w * 16 + q * 4 + r;
            if (rg < N_NODES) {
                float o = fmaxf(acc2[c][r] + bb, 0.f);
                C[(size_t)rg * 64 + col] = f2bf(o);
                psum += o;
                psq += o * o;
            }
        }
        atomicAdd(&ssum[col], psum);
        atomicAdd(&ssq[col], psq);
    }
    __syncthreads();
    if (tid < 128) {
        float v = (tid < 64) ? ssum[tid] : ssq[tid - 64];
        partials[(size_t)blockIdx.x * 128 + tid] = v;
    }
}

// ---------------- pooling + FC + log_softmax ----------------
__global__ void k_pool(const u16* __restrict__ h, const float* __restrict__ ss,
                       const int* __restrict__ gstart, const float* __restrict__ wfc,
                       const float* __restrict__ bfc, float* __restrict__ out) {
    __shared__ float smean[2][128];
    __shared__ float smax[2][128];
    __shared__ float lg[2][8];
    int tid = threadIdx.x;
    int lane = tid & 63;
    int w = tid >> 6;
    int gi = w >> 1;
    int part = w & 1;
    int gr = blockIdx.x * 2 + gi;
    int half = lane >> 5;
    int li = lane & 31;
    int f0 = 2 * li;
    float sc0 = ss[f0], sc1 = ss[f0 + 1];
    float sh0 = ss[64 + f0], sh1 = ss[64 + f0 + 1];
    int s0n = gstart[gr], s1n = gstart[gr + 1];
    int cnt = s1n - s0n;
    int mid = s0n + (cnt >> 1);
    int a = part ? mid : s0n;
    int b = part ? s1n : mid;
    float sum0 = 0.f, sum1 = 0.f, mx0 = -3.4e38f, mx1 = -3.4e38f;
    for (int n = a + half; n < b; n += 2) {
        u32 bits = *(const u32*)(h + (size_t)n * 64 + f0);
        float x0 = fmaf(bflo(bits), sc0, sh0);
        float x1 = fmaf(bfhi(bits), sc1, sh1);
        sum0 += x0; sum1 += x1;
        mx0 = fmaxf(mx0, x0); mx1 = fmaxf(mx1, x1);
    }
    sum0 += __shfl_xor(sum0, 32);
    sum1 += __shfl_xor(sum1, 32);
    mx0 = fmaxf(mx0, __shfl_xor(mx0, 32));
    mx1 = fmaxf(mx1, __shfl_xor(mx1, 32));
    if (half == 0 && part == 0) {
        smean[gi][f0] = sum0; smean[gi][f0 + 1] = sum1;
        smax[gi][f0] = mx0;   smax[gi][f0 + 1] = mx1;
    }
    __syncthreads();
    if (half == 0 && part == 1) {
        float m0 = fmaxf(smax[gi][f0], mx0), m1 = fmaxf(smax[gi][f0 + 1], mx1);
        float t0 = smean[gi][f0] + sum0, t1 = smean[gi][f0 + 1] + sum1;
        float fc = fmaxf((float)cnt, 1.f);
        smean[gi][f0] = t0 / fc;
        smean[gi][f0 + 1] = t1 / fc;
        smax[gi][f0] = (cnt > 0) ? m0 : 0.f;
        smax[gi][f0 + 1] = (cnt > 0) ? m1 : 0.f;
    }
    __syncthreads();
    if (part == 0 && lane < NCLASS) {
        float acc = bfc[lane];
        for (int j = 0; j < 64; ++j) acc = fmaf(smean[gi][j], wfc[j * NCLASS + lane], acc);
        for (int j = 0; j < 64; ++j) acc = fmaf(smax[gi][j], wfc[(64 + j) * NCLASS + lane], acc);
        lg[gi][lane] = acc;
    }
    __syncthreads();
    if (part == 0 && lane < NCLASS) {
        float mm = -3.4e38f;
        for (int c = 0; c < NCLASS; ++c) mm = fmaxf(mm, lg[gi][c]);
        float se = 0.f;
        for (int c = 0; c < NCLASS; ++c) se += expf(lg[gi][c] - mm);
        out[gr * NCLASS + lane] = lg[gi][lane] - mm - logf(se);
    }
}

// ---------------- launch ----------------

extern "C" void kernel_launch(void* const* d_in, const int* in_sizes, int n_in,
                              void* d_out, int out_size, void* d_ws, size_t ws_size,
                              hipStream_t stream) {
    const float* x = (const float*)d_in[0];
    const int* ei = (const int*)d_in[1];
    const int* batch = (const int*)d_in[2];
    const int* esrc_in = ei;
    const int* edst_in = ei + N_EDGES;

    const float* ba[4] = {(const float*)d_in[4], (const float*)d_in[8],
                          (const float*)d_in[12], (const float*)d_in[12]};
    const float* bb[4] = {(const float*)d_in[6], (const float*)d_in[10],
                          (const float*)d_in[14], (const float*)d_in[14]};
    const float* epsv[4] = {(const float*)d_in[15], (const float*)d_in[18],
                            (const float*)d_in[21], (const float*)d_in[24]};
    const float* gg[4] = {(const float*)d_in[16], (const float*)d_in[19],
                          (const float*)d_in[22], (const float*)d_in[25]};
    const float* bee[4] = {(const float*)d_in[17], (const float*)d_in[20],
                           (const float*)d_in[23], (const float*)d_in[26]};
    const float* wfc = (const float*)d_in[27];
    const float* bfc = (const float*)d_in[28];
    float* out = (float*)d_out;

    char* ws = (char*)d_ws;
    int* pairs = (int*)(ws + 0);               // 12,800,000 (dead after k_bsort)
    u16* bufA = (u16*)(ws + 0);                // alias of pairs (first write: layer 1)
    int* esrc = (int*)(ws + 12800000);         // 12,800,000
    u16* xb = (u16*)(ws + 25600000);           // 12,800,000
    u16* bufB = (u16*)(ws + 38400000);         // 12,800,000
    int* rowstart = (int*)(ws + 51200000);     // 400,128
    int* blockhist = (int*)(ws + 51600128);    // 612,352 (padded)
    int* colsum = (int*)(ws + 52212480);       // 2,048
    int* bstart = (int*)(ws + 52214528);       // 2,048
    int* gstart = (int*)(ws + 52216576);       // 2,560
    float* partials = (float*)(ws + 52219136); // 800,768 (padded)
    float* ssbuf = (float*)(ws + 53019904);    // 2,560
    u16* Wtg = (u16*)(ws + 53022464);          // 55,296
    // total: 53,077,760 bytes; no memsets needed

    k_setup<<<CAST_B + 97 + EB + NBLK_NODE, 256, 0, stream>>>(
        x, xb, (const float*)d_in[3], (const float*)d_in[5], (const float*)d_in[7],
        (const float*)d_in[9], (const float*)d_in[11], (const float*)d_in[13],
        Wtg, ssbuf, edst_in, batch, blockhist, gstart);
    k_scan_cols<<<NBUCK, 512, 0, stream>>>(blockhist, colsum);
    k_scan_b<<<1, 512, 0, stream>>>(colsum, bstart, rowstart);
    k_bscatter<<<EB, 256, 0, stream>>>(esrc_in, edst_in, bstart, blockhist, pairs);
    k_bsort<<<NBUCK, 256, 0, stream>>>(pairs, bstart, rowstart, esrc);

    // ping-pong: L0 xb->B, L1 B->A, L2 A->B, L3 B->A; pool reads A
    const u16* hb[4] = {xb, bufB, bufA, bufB};
    u16* cb[4] = {bufB, bufA, bufB, bufA};
    for (int L = 0; L < 4; ++L) {
        const u16* wt = Wtg + (size_t)((L < 2) ? L : 2) * 9216;
        k_layer<<<MLPG, 256, 0, stream>>>(hb[L], ssbuf + L * 128, epsv[L], rowstart,
                                          esrc, wt, ba[L], bb[L], cb[L], partials);
        k_bn<<<64, 256, 0, stream>>>(partials, gg[L], bee[L], ssbuf + (L + 1) * 128);
    }

    k_pool<<<NGRAPH / 2, 256, 0, stream>>>(bufA, ssbuf + 4 * 128, gstart, wfc, bfc, out);
}

// Round 10
// 614.478 us; speedup vs baseline: 1.1388x; 1.1388x over previous
//
#include <hip/hip_runtime.h>

#define N_NODES 100000
#define N_EDGES 3200000
#define NGRAPH 512
#define NCLASS 6
#define BN_EPS 1e-5f

#define BSHIFT 8
#define NBUCK 391          // ceil(100000 / 256)
#define CHUNK 8192         // edges per block in bucket passes
#define EB 391             // ceil(N_EDGES / CHUNK)
#define NBLK_NODE 391      // ceil(N_NODES / 256)
#define MLPG 1563          // ceil(N_NODES / 64) = k_mlp grid = #partials rows
#define CAST_B 6250        // N_NODES*64/4/256 exactly

typedef unsigned short u16;
typedef unsigned int u32;
typedef __attribute__((ext_vector_type(8))) short bf16x8;
typedef __attribute__((ext_vector_type(4))) float f32x4;
typedef __attribute__((ext_vector_type(2))) float f32x2;

__device__ __forceinline__ float bflo(u32 b) {
    u32 t = b << 16; return __builtin_bit_cast(float, t);
}
__device__ __forceinline__ float bfhi(u32 b) {
    u32 t = b & 0xffff0000u; return __builtin_bit_cast(float, t);
}
__device__ __forceinline__ f32x2 bfpair(u32 b) {   // exact {lo, hi} expansion
    return (f32x2){bflo(b), bfhi(b)};               // candidates for v_pk_add_f32
}
__device__ __forceinline__ u16 f2bf(float f) {   // round-to-nearest-even
    u32 u = __builtin_bit_cast(u32, f);
    return (u16)((u + 0x7fffu + ((u >> 16) & 1u)) >> 16);
}

// ---------------- fused setup: cast | weight-prep+ss0 | edge hist | gstart ----------------
__global__ void k_setup(const float* __restrict__ x, u16* __restrict__ xb,
                        const float* __restrict__ W10, const float* __restrict__ W20,
                        const float* __restrict__ W11, const float* __restrict__ W21,
                        const float* __restrict__ W12, const float* __restrict__ W22,
                        u16* __restrict__ Wtg, float* __restrict__ ss0,
                        const int* __restrict__ dst, const int* __restrict__ batch,
                        int* __restrict__ blockhist, int* __restrict__ gstart) {
    __shared__ int hist[NBUCK];
    int b = blockIdx.x;
    int t = threadIdx.x;
    if (b < CAST_B) {
        int base = (b * 256 + t) * 4;
        float4 v = *(const float4*)(x + base);
        ushort4 o = make_ushort4(f2bf(v.x), f2bf(v.y), f2bf(v.z), f2bf(v.w));
        *(ushort4*)(xb + base) = o;
    } else if (b < CAST_B + 97) {
        int bb = b - CAST_B;
        if (bb < 96) {
            int e = bb * 256 + t;          // < 24576 = 6 * 4096
            int mat = e >> 12;
            int i = e & 4095;
            const float* s = (mat == 0) ? W10 : (mat == 1) ? W20 : (mat == 2) ? W11
                           : (mat == 3) ? W21 : (mat == 4) ? W12 : W22;
            float v = s[i];
            int k = i >> 6, c = i & 63;
            Wtg[mat * 4608 + c * 72 + k] = f2bf(v);
        } else {
            if (t < 64) ss0[t] = 1.0f;
            else if (t < 128) ss0[t] = 0.0f;
        }
    } else if (b < CAST_B + 97 + EB) {
        int be = b - (CAST_B + 97);
        long e0 = (long)be * CHUNK;
        for (int i = t; i < NBUCK; i += 256) hist[i] = 0;
        __syncthreads();
        for (int i = t; i < CHUNK; i += 256) {
            long e = e0 + i;
            if (e < N_EDGES) atomicAdd(&hist[dst[e] >> BSHIFT], 1);
        }
        __syncthreads();
        for (int i = t; i < NBUCK; i += 256) blockhist[be * NBUCK + i] = hist[i];
    } else {
        int i = (b - (CAST_B + 97 + EB)) * 256 + t;
        if (i < N_NODES) {
            int bi = batch[i];
            int bp = (i == 0) ? -1 : batch[i - 1];
            for (int g = bp + 1; g <= bi; ++g) gstart[g] = i;
            if (i == N_NODES - 1)
                for (int g = bi + 1; g <= NGRAPH; ++g) gstart[g] = N_NODES;
        }
    }
}

// ---------------- CSR build (unchanged) ----------------

__global__ void k_scan_cols(int* __restrict__ blockhist, int* __restrict__ colsum) {
    __shared__ int sh[512];
    int k = blockIdx.x;
    int t = threadIdx.x;
    int v = (t < EB) ? blockhist[t * NBUCK + k] : 0;
    sh[t] = v;
    __syncthreads();
    for (int off = 1; off < 512; off <<= 1) {
        int x = (t >= off) ? sh[t - off] : 0;
        __syncthreads();
        sh[t] += x;
        __syncthreads();
    }
    if (t < EB) blockhist[t * NBUCK + k] = sh[t] - v;
    if (t == 511) colsum[k] = sh[511];
}

__global__ void k_scan_b(const int* __restrict__ colsum, int* __restrict__ bstart,
                         int* __restrict__ rowstart) {
    __shared__ int sh[512];
    int t = threadIdx.x;
    int v = (t < NBUCK) ? colsum[t] : 0;
    sh[t] = v;
    __syncthreads();
    for (int off = 1; off < 512; off <<= 1) {
        int x = (t >= off) ? sh[t - off] : 0;
        __syncthreads();
        sh[t] += x;
        __syncthreads();
    }
    if (t < NBUCK) bstart[t] = sh[t] - v;
    if (t == NBUCK - 1) bstart[NBUCK] = sh[t];
    if (t == 0) rowstart[N_NODES] = N_EDGES;
}

__global__ void k_bscatter(const int* __restrict__ src, const int* __restrict__ dst,
                           const int* __restrict__ bstart,
                           const int* __restrict__ blockhist, int* __restrict__ pairs) {
    __shared__ int base[NBUCK];
    __shared__ int hist[NBUCK];
    int tid = threadIdx.x;
    int b = blockIdx.x;
    long e0 = (long)b * CHUNK;
    for (int k = tid; k < NBUCK; k += 256) {
        base[k] = bstart[k] + blockhist[b * NBUCK + k];
        hist[k] = 0;
    }
    __syncthreads();
    for (int i = tid; i < CHUNK; i += 256) {
        long e = e0 + i;
        if (e < N_EDGES) {
            int d = dst[e];
            int k = d >> BSHIFT;
            int r = atomicAdd(&hist[k], 1);
            pairs[base[k] + r] = (src[e] << 8) | (d & 255);
        }
    }
}

__global__ void k_bsort(const int* __restrict__ pairs, const int* __restrict__ bstart,
                        int* __restrict__ rowstart, int* __restrict__ esrc) {
    __shared__ int deg[256];
    __shared__ int cur[256];
    int b = blockIdx.x;
    int tid = threadIdx.x;
    int p0 = bstart[b], p1 = bstart[b + 1];
    deg[tid] = 0;
    __syncthreads();
    for (int i = p0 + tid; i < p1; i += 256)
        atomicAdd(&deg[pairs[i] & 255], 1);
    __syncthreads();
    int v = deg[tid];
    cur[tid] = v;
    __syncthreads();
    for (int off = 1; off < 256; off <<= 1) {
        int x = (tid >= off) ? cur[tid - off] : 0;
        __syncthreads();
        cur[tid] += x;
        __syncthreads();
    }
    int excl = cur[tid] - v;
    int node = (b << BSHIFT) + tid;
    if (node < N_NODES) rowstart[node] = p0 + excl;
    __syncthreads();
    cur[tid] = excl;
    __syncthreads();
    for (int i = p0 + tid; i < p1; i += 256) {
        u32 pr = (u32)pairs[i];
        int r = atomicAdd(&cur[pr & 255], 1);
        esrc[p0 + r] = (int)(pr >> 8);
    }
}

// ---------------- BN fold: reduce partials -> scale/shift ----------------
__global__ void k_bn(const float* __restrict__ partials, const float* __restrict__ g,
                     const float* __restrict__ be, float* __restrict__ ss) {
    __shared__ float sS[256];
    __shared__ float sQ[256];
    int f = blockIdx.x;
    int t = threadIdx.x;
    float aS = 0.f, aQ = 0.f;
    for (int b = t; b < MLPG; b += 256) {
        aS += partials[b * 128 + f];
        aQ += partials[b * 128 + 64 + f];
    }
    sS[t] = aS; sQ[t] = aQ;
    __syncthreads();
    for (int off = 128; off >= 1; off >>= 1) {
        if (t < off) { sS[t] += sS[t + off]; sQ[t] += sQ[t + off]; }
        __syncthreads();
    }
    if (t == 0) {
        float mu = sS[0] / (float)N_NODES;
        float var = fmaxf(sQ[0] / (float)N_NODES - mu * mu, 0.f);
        float sc = g[f] * rsqrtf(var + BN_EPS);
        ss[f] = sc;
        ss[64 + f] = be[f] - mu * sc;
    }
}

// ---------------- aggregation (R8 structure; float2 packed accumulate) ----------------
// One wave per dst node; lane group g=lane>>3 handles edge j+g; each lane owns
// 8 features = 16B. Accumulation in f32x2 {lo,hi} (exact shift/and extraction,
// same numerics as R8) to enable v_pk_add_f32. All shfls all-lanes-active
// with clamped in-range sources.
__global__ void k_agg(const u16* __restrict__ hin, const float* __restrict__ ss,
                      const float* __restrict__ epsp, const int* __restrict__ rowstart,
                      const int* __restrict__ esrc, u16* __restrict__ out) {
    int lane = threadIdx.x & 63;
    int wid = threadIdx.x >> 6;
    int node = blockIdx.x * 4 + wid;
    if (node >= N_NODES) return;
    int grp = lane >> 3;
    int f0 = 8 * (lane & 7);
    f32x2 ac0 = {0.f, 0.f}, ac1 = {0.f, 0.f}, ac2 = {0.f, 0.f}, ac3 = {0.f, 0.f};
    int e0 = rowstart[node], e1 = rowstart[node + 1];
    for (int i = e0; i < e1; i += 64) {
        int cnt = min(e1 - i, 64);
        int src = (lane < cnt) ? esrc[i + lane] : 0;
        int j = 0;
        for (; j + 16 <= cnt; j += 16) {   // 2 loads in flight
            int a = __shfl(src, j + grp);
            int b = __shfl(src, j + 8 + grp);
            uint4 va = *(const uint4*)(hin + (size_t)a * 64 + f0);
            uint4 vb = *(const uint4*)(hin + (size_t)b * 64 + f0);
            ac0 += bfpair(va.x); ac1 += bfpair(va.y);
            ac2 += bfpair(va.z); ac3 += bfpair(va.w);
            ac0 += bfpair(vb.x); ac1 += bfpair(vb.y);
            ac2 += bfpair(vb.z); ac3 += bfpair(vb.w);
        }
        if (j + 8 <= cnt) {
            int a = __shfl(src, j + grp);
            uint4 va = *(const uint4*)(hin + (size_t)a * 64 + f0);
            ac0 += bfpair(va.x); ac1 += bfpair(va.y);
            ac2 += bfpair(va.z); ac3 += bfpair(va.w);
            j += 8;
        }
        if (j < cnt) {                      // <8 remainder: clamp src, gate adds
            int jj = j + grp;
            int a = __shfl(src, (jj < cnt) ? jj : (cnt - 1));
            uint4 va = *(const uint4*)(hin + (size_t)a * 64 + f0);
            if (jj < cnt) {
                ac0 += bfpair(va.x); ac1 += bfpair(va.y);
                ac2 += bfpair(va.z); ac3 += bfpair(va.w);
            }
        }
    }
    float acc[8] = {ac0.x, ac0.y, ac1.x, ac1.y, ac2.x, ac2.y, ac3.x, ac3.y};
    #pragma unroll
    for (int k = 0; k < 8; ++k) {
        acc[k] += __shfl_xor(acc[k], 8);
        acc[k] += __shfl_xor(acc[k], 16);
        acc[k] += __shfl_xor(acc[k], 32);
    }
    float epsv = 1.0f + epsp[0];
    float deg = (float)(e1 - e0);
    uint4 sb = *(const uint4*)(hin + (size_t)node * 64 + f0);
    float self[8] = {bflo(sb.x), bfhi(sb.x), bflo(sb.y), bfhi(sb.y),
                     bflo(sb.z), bfhi(sb.z), bflo(sb.w), bfhi(sb.w)};
    float4 scA = *(const float4*)(ss + f0);
    float4 scB = *(const float4*)(ss + f0 + 4);
    float4 shA = *(const float4*)(ss + 64 + f0);
    float4 shB = *(const float4*)(ss + 64 + f0 + 4);
    float sc[8] = {scA.x, scA.y, scA.z, scA.w, scB.x, scB.y, scB.z, scB.w};
    float sh[8] = {shA.x, shA.y, shA.z, shA.w, shB.x, shB.y, shB.z, shB.w};
    if (grp == 0) {
        u32 pk[4];
        #pragma unroll
        for (int k = 0; k < 4; ++k) {
            float oa = sc[2 * k] * (acc[2 * k] + epsv * self[2 * k]) +
                       (deg + epsv) * sh[2 * k];
            float ob = sc[2 * k + 1] * (acc[2 * k + 1] + epsv * self[2 * k + 1]) +
                       (deg + epsv) * sh[2 * k + 1];
            pk[k] = (u32)f2bf(oa) | ((u32)f2bf(ob) << 16);
        }
        uint4 po = make_uint4(pk[0], pk[1], pk[2], pk[3]);
        *(uint4*)(out + (size_t)node * 64 + f0) = po;
    }
}

// ---------------- fused MLP via bf16 MFMA ----------------
// B-fragments (weights, 18KB) read DIRECTLY from global — L2-hot in every XCD
// (~100MB aggregate / 34TB/s ≈ 3us). LDS = Hs only -> ~2x blocks/CU vs R8.
// Stats: per-block coalesced stores to partials (no global atomics).
__global__ __launch_bounds__(256) void k_mlp(
    const u16* __restrict__ A, const u16* __restrict__ Wt,
    const float* __restrict__ b1, const float* __restrict__ b2,
    u16* __restrict__ C, float* __restrict__ partials) {
    __shared__ __align__(16) u16 Hs[64 * 72];
    __shared__ float ssum[64];
    __shared__ float ssq[64];
    int tid = threadIdx.x;
    int r0 = blockIdx.x * 64;
    if (tid < 64) { ssum[tid] = 0.f; ssq[tid] = 0.f; }
    __syncthreads();
    const u16* Wt2 = Wt + 4608;

    int lane = tid & 63;
    int w = tid >> 6;
    int m = lane & 15;
    int q = lane >> 4;
    int rowg = r0 + w * 16 + m;
    int rowc = min(rowg, N_NODES - 1);

    bf16x8 a0 = *(const bf16x8*)(A + (size_t)rowc * 64 + q * 8);
    bf16x8 a1 = *(const bf16x8*)(A + (size_t)rowc * 64 + 32 + q * 8);
    f32x4 acc[4];
    #pragma unroll
    for (int c = 0; c < 4; ++c) {
        acc[c] = (f32x4){0.f, 0.f, 0.f, 0.f};
        bf16x8 bA = *(const bf16x8*)(Wt + (c * 16 + m) * 72 + q * 8);
        bf16x8 bB = *(const bf16x8*)(Wt + (c * 16 + m) * 72 + 32 + q * 8);
        acc[c] = __builtin_amdgcn_mfma_f32_16x16x32_bf16(a0, bA, acc[c], 0, 0, 0);
        acc[c] = __builtin_amdgcn_mfma_f32_16x16x32_bf16(a1, bB, acc[c], 0, 0, 0);
    }
    #pragma unroll
    for (int c = 0; c < 4; ++c) {
        int col = c * 16 + m;
        float bb = b1[col];
        #pragma unroll
        for (int r = 0; r < 4; ++r) {
            int rl = w * 16 + q * 4 + r;
            Hs[rl * 72 + col] = f2bf(fmaxf(acc[c][r] + bb, 0.f));
        }
    }
    bf16x8 h0 = *(const bf16x8*)(&Hs[(w * 16 + m) * 72 + q * 8]);
    bf16x8 h1 = *(const bf16x8*)(&Hs[(w * 16 + m) * 72 + 32 + q * 8]);
    f32x4 acc2[4];
    #pragma unroll
    for (int c = 0; c < 4; ++c) {
        acc2[c] = (f32x4){0.f, 0.f, 0.f, 0.f};
        bf16x8 bA = *(const bf16x8*)(Wt2 + (c * 16 + m) * 72 + q * 8);
        bf16x8 bB = *(const bf16x8*)(Wt2 + (c * 16 + m) * 72 + 32 + q * 8);
        acc2[c] = __builtin_amdgcn_mfma_f32_16x16x32_bf16(h0, bA, acc2[c], 0, 0, 0);
        acc2[c] = __builtin_amdgcn_mfma_f32_16x16x32_bf16(h1, bB, acc2[c], 0, 0, 0);
    }
    #pragma unroll
    for (int c = 0; c < 4; ++c) {
        int col = c * 16 + m;
        float bb = b2[col];
        float psum = 0.f, psq = 0.f;
        #pragma unroll
        for (int r = 0; r < 4; ++r) {
            int rg = r0 + w * 16 + q * 4 + r;
            if (rg < N_NODES) {
                float o = fmaxf(acc2[c][r] + bb, 0.f);
                C[(size_t)rg * 64 + col] = f2bf(o);
                psum += o;
                psq += o * o;
            }
        }
        atomicAdd(&ssum[col], psum);
        atomicAdd(&ssq[col], psq);
    }
    __syncthreads();
    if (tid < 128) {
        float v = (tid < 64) ? ssum[tid] : ssq[tid - 64];
        partials[(size_t)blockIdx.x * 128 + tid] = v;
    }
}

// ---------------- pooling + FC + log_softmax ----------------
__global__ void k_pool(const u16* __restrict__ h, const float* __restrict__ ss,
                       const int* __restrict__ gstart, const float* __restrict__ wfc,
                       const float* __restrict__ bfc, float* __restrict__ out) {
    __shared__ float smean[2][128];
    __shared__ float smax[2][128];
    __shared__ float lg[2][8];
    int tid = threadIdx.x;
    int lane = tid & 63;
    int w = tid >> 6;
    int gi = w >> 1;
    int part = w & 1;
    int gr = blockIdx.x * 2 + gi;
    int half = lane >> 5;
    int li = lane & 31;
    int f0 = 2 * li;
    float sc0 = ss[f0], sc1 = ss[f0 + 1];
    float sh0 = ss[64 + f0], sh1 = ss[64 + f0 + 1];
    int s0n = gstart[gr], s1n = gstart[gr + 1];
    int cnt = s1n - s0n;
    int mid = s0n + (cnt >> 1);
    int a = part ? mid : s0n;
    int b = part ? s1n : mid;
    float sum0 = 0.f, sum1 = 0.f, mx0 = -3.4e38f, mx1 = -3.4e38f;
    for (int n = a + half; n < b; n += 2) {
        u32 bits = *(const u32*)(h + (size_t)n * 64 + f0);
        float x0 = fmaf(bflo(bits), sc0, sh0);
        float x1 = fmaf(bfhi(bits), sc1, sh1);
        sum0 += x0; sum1 += x1;
        mx0 = fmaxf(mx0, x0); mx1 = fmaxf(mx1, x1);
    }
    sum0 += __shfl_xor(sum0, 32);
    sum1 += __shfl_xor(sum1, 32);
    mx0 = fmaxf(mx0, __shfl_xor(mx0, 32));
    mx1 = fmaxf(mx1, __shfl_xor(mx1, 32));
    if (half == 0 && part == 0) {
        smean[gi][f0] = sum0; smean[gi][f0 + 1] = sum1;
        smax[gi][f0] = mx0;   smax[gi][f0 + 1] = mx1;
    }
    __syncthreads();
    if (half == 0 && part == 1) {
        float m0 = fmaxf(smax[gi][f0], mx0), m1 = fmaxf(smax[gi][f0 + 1], mx1);
        float t0 = smean[gi][f0] + sum0, t1 = smean[gi][f0 + 1] + sum1;
        float fc = fmaxf((float)cnt, 1.f);
        smean[gi][f0] = t0 / fc;
        smean[gi][f0 + 1] = t1 / fc;
        smax[gi][f0] = (cnt > 0) ? m0 : 0.f;
        smax[gi][f0 + 1] = (cnt > 0) ? m1 : 0.f;
    }
    __syncthreads();
    if (part == 0 && lane < NCLASS) {
        float acc = bfc[lane];
        for (int j = 0; j < 64; ++j) acc = fmaf(smean[gi][j], wfc[j * NCLASS + lane], acc);
        for (int j = 0; j < 64; ++j) acc = fmaf(smax[gi][j], wfc[(64 + j) * NCLASS + lane], acc);
        lg[gi][lane] = acc;
    }
    __syncthreads();
    if (part == 0 && lane < NCLASS) {
        float mm = -3.4e38f;
        for (int c = 0; c < NCLASS; ++c) mm = fmaxf(mm, lg[gi][c]);
        float se = 0.f;
        for (int c = 0; c < NCLASS; ++c) se += expf(lg[gi][c] - mm);
        out[gr * NCLASS + lane] = lg[gi][lane] - mm - logf(se);
    }
}

// ---------------- launch ----------------

extern "C" void kernel_launch(void* const* d_in, const int* in_sizes, int n_in,
                              void* d_out, int out_size, void* d_ws, size_t ws_size,
                              hipStream_t stream) {
    const float* x = (const float*)d_in[0];
    const int* ei = (const int*)d_in[1];
    const int* batch = (const int*)d_in[2];
    const int* esrc_in = ei;
    const int* edst_in = ei + N_EDGES;

    const float* ba[4] = {(const float*)d_in[4], (const float*)d_in[8],
                          (const float*)d_in[12], (const float*)d_in[12]};
    const float* bb[4] = {(const float*)d_in[6], (const float*)d_in[10],
                          (const float*)d_in[14], (const float*)d_in[14]};
    const float* epsv[4] = {(const float*)d_in[15], (const float*)d_in[18],
                            (const float*)d_in[21], (const float*)d_in[24]};
    const float* gg[4] = {(const float*)d_in[16], (const float*)d_in[19],
                          (const float*)d_in[22], (const float*)d_in[25]};
    const float* bee[4] = {(const float*)d_in[17], (const float*)d_in[20],
                           (const float*)d_in[23], (const float*)d_in[26]};
    const float* wfc = (const float*)d_in[27];
    const float* bfc = (const float*)d_in[28];
    float* out = (float*)d_out;

    char* ws = (char*)d_ws;
    int* pairs = (int*)(ws + 0);               // 12,800,000 (dead after k_bsort)
    u16* bufA = (u16*)(ws + 0);                // alias of pairs
    int* esrc = (int*)(ws + 12800000);         // 12,800,000
    u16* xb = (u16*)(ws + 25600000);           // 12,800,000
    u16* bufB = (u16*)(ws + 38400000);         // 12,800,000
    int* rowstart = (int*)(ws + 51200000);     // 400,128
    int* blockhist = (int*)(ws + 51600128);    // 612,352 (padded)
    int* colsum = (int*)(ws + 52212480);       // 2,048
    int* bstart = (int*)(ws + 52214528);       // 2,048
    int* gstart = (int*)(ws + 52216576);       // 2,560
    float* partials = (float*)(ws + 52219136); // 800,768 (padded)
    float* ssbuf = (float*)(ws + 53019904);    // 2,560
    u16* Wtg = (u16*)(ws + 53022464);          // 55,296
    // total: 53,077,760 bytes; no memsets needed

    k_setup<<<CAST_B + 97 + EB + NBLK_NODE, 256, 0, stream>>>(
        x, xb, (const float*)d_in[3], (const float*)d_in[5], (const float*)d_in[7],
        (const float*)d_in[9], (const float*)d_in[11], (const float*)d_in[13],
        Wtg, ssbuf, edst_in, batch, blockhist, gstart);
    k_scan_cols<<<NBUCK, 512, 0, stream>>>(blockhist, colsum);
    k_scan_b<<<1, 512, 0, stream>>>(colsum, bstart, rowstart);
    k_bscatter<<<EB, 256, 0, stream>>>(esrc_in, edst_in, bstart, blockhist, pairs);
    k_bsort<<<NBUCK, 256, 0, stream>>>(pairs, bstart, rowstart, esrc);

    const int AGG_GRID = (N_NODES + 3) / 4;
    for (int L = 0; L < 4; ++L) {
        const u16* hin = (L == 0) ? xb : bufB;
        const u16* wt = Wtg + (size_t)((L < 2) ? L : 2) * 9216;
        k_agg<<<AGG_GRID, 256, 0, stream>>>(hin, ssbuf + L * 128, epsv[L], rowstart,
                                            esrc, bufA);
        k_mlp<<<MLPG, 256, 0, stream>>>(bufA, wt, ba[L], bb[L], bufB, partials);
        k_bn<<<64, 256, 0, stream>>>(partials, gg[L], bee[L], ssbuf + (L + 1) * 128);
    }

    k_pool<<<NGRAPH / 2, 256, 0, stream>>>(bufB, ssbuf + 4 * 128, gstart, wfc, bfc, out);
}

// Round 11
// 543.141 us; speedup vs baseline: 1.2884x; 1.1313x over previous
//
#include <hip/hip_runtime.h>

#define N_NODES 100000
#define N_EDGES 3200000
#define NGRAPH 512
#define NCLASS 6
#define BN_EPS 1e-5f

#define BSHIFT 8
#define NBUCK 391          // ceil(100000 / 256)
#define CHUNK 8192         // edges per block in bucket passes
#define EB 391             // ceil(N_EDGES / CHUNK)
#define NBLK_NODE 391      // ceil(N_NODES / 256)
#define FUSG 3125          // k_fused grid: 2 waves/block x 16 nodes = 32 nodes/block
#define NPART 6250         // partials rows = one per wave
#define CAST_B 6250        // N_NODES*64/4/256 exactly
#define BSMAX 12032        // k_bsort LDS capacity (mean 8192 + 42 sigma)

typedef unsigned short u16;
typedef unsigned int u32;
typedef __attribute__((ext_vector_type(8))) short bf16x8;
typedef __attribute__((ext_vector_type(4))) float f32x4;
typedef __attribute__((ext_vector_type(2))) float f32x2;

__device__ __forceinline__ float bflo(u32 b) {
    u32 t = b << 16; return __builtin_bit_cast(float, t);
}
__device__ __forceinline__ float bfhi(u32 b) {
    u32 t = b & 0xffff0000u; return __builtin_bit_cast(float, t);
}
__device__ __forceinline__ f32x2 bfpair(u32 b) {
    return (f32x2){bflo(b), bfhi(b)};
}
__device__ __forceinline__ u16 f2bf(float f) {   // round-to-nearest-even
    u32 u = __builtin_bit_cast(u32, f);
    return (u16)((u + 0x7fffu + ((u >> 16) & 1u)) >> 16);
}

// ---------------- fused setup: cast | weight-prep+ss0 | edge hist | gstart ----------------
__global__ void k_setup(const float* __restrict__ x, u16* __restrict__ xb,
                        const float* __restrict__ W10, const float* __restrict__ W20,
                        const float* __restrict__ W11, const float* __restrict__ W21,
                        const float* __restrict__ W12, const float* __restrict__ W22,
                        u16* __restrict__ Wtg, float* __restrict__ ss0,
                        const int* __restrict__ dst, const int* __restrict__ batch,
                        int* __restrict__ blockhist, int* __restrict__ gstart,
                        int* __restrict__ rowstart) {
    __shared__ int hist[NBUCK];
    int b = blockIdx.x;
    int t = threadIdx.x;
    if (b < CAST_B) {
        int base = (b * 256 + t) * 4;
        float4 v = *(const float4*)(x + base);
        ushort4 o = make_ushort4(f2bf(v.x), f2bf(v.y), f2bf(v.z), f2bf(v.w));
        *(ushort4*)(xb + base) = o;
    } else if (b < CAST_B + 97) {
        int bb = b - CAST_B;
        if (bb < 96) {
            int e = bb * 256 + t;          // < 24576 = 6 * 4096
            int mat = e >> 12;
            int i = e & 4095;
            const float* s = (mat == 0) ? W10 : (mat == 1) ? W20 : (mat == 2) ? W11
                           : (mat == 3) ? W21 : (mat == 4) ? W12 : W22;
            float v = s[i];
            int k = i >> 6, c = i & 63;
            Wtg[mat * 4608 + c * 72 + k] = f2bf(v);
        } else {
            if (t < 64) ss0[t] = 1.0f;
            else if (t < 128) ss0[t] = 0.0f;
            else if (t == 128) rowstart[N_NODES] = N_EDGES;
        }
    } else if (b < CAST_B + 97 + EB) {
        int be = b - (CAST_B + 97);
        long e0 = (long)be * CHUNK;
        for (int i = t; i < NBUCK; i += 256) hist[i] = 0;
        __syncthreads();
        for (int i = t; i < CHUNK; i += 256) {
            long e = e0 + i;
            if (e < N_EDGES) atomicAdd(&hist[dst[e] >> BSHIFT], 1);
        }
        __syncthreads();
        for (int i = t; i < NBUCK; i += 256) blockhist[be * NBUCK + i] = hist[i];
    } else {
        int i = (b - (CAST_B + 97 + EB)) * 256 + t;
        if (i < N_NODES) {
            int bi = batch[i];
            int bp = (i == 0) ? -1 : batch[i - 1];
            for (int g = bp + 1; g <= bi; ++g) gstart[g] = i;
            if (i == N_NODES - 1)
                for (int g = bi + 1; g <= NGRAPH; ++g) gstart[g] = N_NODES;
        }
    }
}

// one block per bucket k: exclusive-scan blockhist column k (in place) + total.
__global__ void k_scan_cols(int* __restrict__ blockhist, int* __restrict__ colsum) {
    __shared__ int sh[512];
    int k = blockIdx.x;
    int t = threadIdx.x;
    int v = (t < EB) ? blockhist[t * NBUCK + k] : 0;
    sh[t] = v;
    __syncthreads();
    for (int off = 1; off < 512; off <<= 1) {
        int x = (t >= off) ? sh[t - off] : 0;
        __syncthreads();
        sh[t] += x;
        __syncthreads();
    }
    if (t < EB) blockhist[t * NBUCK + k] = sh[t] - v;
    if (t == 511) colsum[k] = sh[511];
}

// LDS-staged bucket scatter: sort the chunk's edges by bucket in LDS, then
// write bucket-runs COALESCED (R1 lesson: scattered 4B stores -> 15x write
// amplification). bstart computed in-LDS from colsum (k_scan_b deleted).
__global__ __launch_bounds__(512) void k_bscatter(
    const int* __restrict__ src, const int* __restrict__ dst,
    const int* __restrict__ colsum, const int* __restrict__ blockhist,
    int* __restrict__ pairs) {
    __shared__ int sh[512];
    __shared__ int bstart_s[NBUCK];
    __shared__ int cnt[NBUCK];
    __shared__ int cur[NBUCK];
    __shared__ int gbase[NBUCK];
    __shared__ u32 sorted[CHUNK];
    __shared__ u16 kbuf[CHUNK];
    int t = threadIdx.x;
    int b = blockIdx.x;
    long e0 = (long)b * CHUNK;
    int v = (t < NBUCK) ? colsum[t] : 0;
    sh[t] = v;
    if (t < NBUCK) cnt[t] = 0;
    __syncthreads();
    for (int off = 1; off < 512; off <<= 1) {
        int x = (t >= off) ? sh[t - off] : 0;
        __syncthreads();
        sh[t] += x;
        __syncthreads();
    }
    if (t < NBUCK) bstart_s[t] = sh[t] - v;
    __syncthreads();
    for (int i = t; i < CHUNK; i += 512) {
        long e = e0 + i;
        if (e < N_EDGES) atomicAdd(&cnt[dst[e] >> BSHIFT], 1);
    }
    __syncthreads();
    int c = (t < NBUCK) ? cnt[t] : 0;
    sh[t] = c;
    __syncthreads();
    for (int off = 1; off < 512; off <<= 1) {
        int x = (t >= off) ? sh[t - off] : 0;
        __syncthreads();
        sh[t] += x;
        __syncthreads();
    }
    if (t < NBUCK) {
        int excl = sh[t] - c;
        cur[t] = excl;
        gbase[t] = bstart_s[t] + blockhist[b * NBUCK + t] - excl;
    }
    __syncthreads();
    for (int i = t; i < CHUNK; i += 512) {
        long e = e0 + i;
        if (e < N_EDGES) {
            int d = dst[e];
            int k = d >> BSHIFT;
            int r = atomicAdd(&cur[k], 1);
            sorted[r] = ((u32)src[e] << 8) | (u32)(d & 255);
            kbuf[r] = (u16)k;
        }
    }
    __syncthreads();
    int tot = (int)min((long)CHUNK, (long)N_EDGES - e0);
    for (int i = t; i < tot; i += 512)
        pairs[gbase[kbuf[i]] + i] = (int)sorted[i];
}

// per-bucket fine counting sort; LDS-staged output -> coalesced esrc writes.
__global__ __launch_bounds__(512) void k_bsort(
    const int* __restrict__ pairs, const int* __restrict__ colsum,
    int* __restrict__ rowstart, int* __restrict__ esrc) {
    __shared__ int sh[512];
    __shared__ int deg[256];
    __shared__ int cur[256];
    __shared__ u32 ssrc[BSMAX];
    int b = blockIdx.x;
    int t = threadIdx.x;
    int v = (t < NBUCK) ? colsum[t] : 0;
    sh[t] = v;
    if (t < 256) deg[t] = 0;
    __syncthreads();
    for (int off = 1; off < 512; off <<= 1) {
        int x = (t >= off) ? sh[t - off] : 0;
        __syncthreads();
        sh[t] += x;
        __syncthreads();
    }
    int p0 = (b == 0) ? 0 : sh[b - 1];
    int p1 = sh[b];
    int n = p1 - p0;
    __syncthreads();
    for (int i = p0 + t; i < p1; i += 512)
        atomicAdd(&deg[pairs[i] & 255], 1);
    __syncthreads();
    if (t < 256) sh[t] = deg[t];
    __syncthreads();
    for (int off = 1; off < 256; off <<= 1) {
        int x = (t >= off && t < 256) ? sh[t - off] : 0;
        __syncthreads();
        if (t < 256) sh[t] += x;
        __syncthreads();
    }
    if (t < 256) {
        int excl = sh[t] - deg[t];
        cur[t] = excl;
        int node = (b << BSHIFT) + t;
        if (node < N_NODES) rowstart[node] = p0 + excl;
    }
    __syncthreads();
    if (n <= BSMAX) {
        for (int i = p0 + t; i < p1; i += 512) {
            u32 pr = (u32)pairs[i];
            int r = atomicAdd(&cur[pr & 255], 1);
            ssrc[r] = pr >> 8;
        }
        __syncthreads();
        for (int i = t; i < n; i += 512) esrc[p0 + i] = (int)ssrc[i];
    } else {   // statistical impossibility; correctness fallback
        for (int i = p0 + t; i < p1; i += 512) {
            u32 pr = (u32)pairs[i];
            int r = atomicAdd(&cur[pr & 255], 1);
            esrc[p0 + r] = (int)(pr >> 8);
        }
    }
}

// ---------------- BN fold: reduce partials -> scale/shift ----------------
__global__ void k_bn(const float* __restrict__ partials, const float* __restrict__ g,
                     const float* __restrict__ be, float* __restrict__ ss) {
    __shared__ float sS[256];
    __shared__ float sQ[256];
    int f = blockIdx.x;
    int t = threadIdx.x;
    float aS = 0.f, aQ = 0.f;
    for (int b = t; b < NPART; b += 256) {
        aS += partials[b * 128 + f];
        aQ += partials[b * 128 + 64 + f];
    }
    sS[t] = aS; sQ[t] = aQ;
    __syncthreads();
    for (int off = 128; off >= 1; off >>= 1) {
        if (t < off) { sS[t] += sS[t + off]; sQ[t] += sQ[t + off]; }
        __syncthreads();
    }
    if (t == 0) {
        float mu = sS[0] / (float)N_NODES;
        float var = fmaxf(sQ[0] / (float)N_NODES - mu * mu, 0.f);
        float sc = g[f] * rsqrtf(var + BN_EPS);
        ss[f] = sc;
        ss[64 + f] = be[f] - mu * sc;
    }
}

// ---------------- fused GIN layer: per-WAVE agg -> LDS -> MFMA (no barrier) ----------------
// Each wave owns 16 nodes: aggregates them sequentially (R10 k_agg body), writes
// bf16 rows into its private LDS tile, then runs the R10 k_mlp MFMA phase on its
// own tile. NO __syncthreads: all LDS deps are same-wave (in-order DS per wave).
// R9's fusion failed on grid size (1563) + block barrier; here: 3125 blocks x
// 2 independent waves, launch_bounds(128,5) caps VGPR ~102 -> ~20 waves/CU.
__global__ __launch_bounds__(128, 5) void k_fused(
    const u16* __restrict__ hin, const float* __restrict__ ss,
    const float* __restrict__ epsp, const int* __restrict__ rowstart,
    const int* __restrict__ esrc, const u16* __restrict__ Wt,
    const float* __restrict__ b1, const float* __restrict__ b2,
    u16* __restrict__ C, float* __restrict__ partials) {
    __shared__ __align__(16) u16 Ain[2][16 * 72];
    __shared__ __align__(16) u16 Hs[2][16 * 72];
    int lane = threadIdx.x & 63;
    int wid = threadIdx.x >> 6;
    int r0 = blockIdx.x * 32 + wid * 16;

    // ---- phase A: aggregate 16 nodes (R10 k_agg body per node) ----
    int grp = lane >> 3;
    int f0 = 8 * (lane & 7);
    float epsv = 1.0f + epsp[0];
    float4 scA = *(const float4*)(ss + f0);
    float4 scB = *(const float4*)(ss + f0 + 4);
    float4 shA = *(const float4*)(ss + 64 + f0);
    float4 shB = *(const float4*)(ss + 64 + f0 + 4);
    float sc[8] = {scA.x, scA.y, scA.z, scA.w, scB.x, scB.y, scB.z, scB.w};
    float sh[8] = {shA.x, shA.y, shA.z, shA.w, shB.x, shB.y, shB.z, shB.w};

    for (int t = 0; t < 16; ++t) {
        int node = r0 + t;
        u32* arow = (u32*)&Ain[wid][0] + t * 36 + (lane & 7) * 4;
        if (node < N_NODES) {
            f32x2 ac0 = {0.f, 0.f}, ac1 = {0.f, 0.f}, ac2 = {0.f, 0.f}, ac3 = {0.f, 0.f};
            int e0 = rowstart[node], e1 = rowstart[node + 1];
            for (int i = e0; i < e1; i += 64) {
                int cnt = min(e1 - i, 64);
                int src = (lane < cnt) ? esrc[i + lane] : 0;
                int j = 0;
                for (; j + 16 <= cnt; j += 16) {
                    int a = __shfl(src, j + grp);
                    int b = __shfl(src, j + 8 + grp);
                    uint4 va = *(const uint4*)(hin + (size_t)a * 64 + f0);
                    uint4 vb = *(const uint4*)(hin + (size_t)b * 64 + f0);
                    ac0 += bfpair(va.x); ac1 += bfpair(va.y);
                    ac2 += bfpair(va.z); ac3 += bfpair(va.w);
                    ac0 += bfpair(vb.x); ac1 += bfpair(vb.y);
                    ac2 += bfpair(vb.z); ac3 += bfpair(vb.w);
                }
                if (j + 8 <= cnt) {
                    int a = __shfl(src, j + grp);
                    uint4 va = *(const uint4*)(hin + (size_t)a * 64 + f0);
                    ac0 += bfpair(va.x); ac1 += bfpair(va.y);
                    ac2 += bfpair(va.z); ac3 += bfpair(va.w);
                    j += 8;
                }
                if (j < cnt) {   // clamp src (all lanes active), gate accumulate
                    int jj = j + grp;
                    int a = __shfl(src, (jj < cnt) ? jj : (cnt - 1));
                    uint4 va = *(const uint4*)(hin + (size_t)a * 64 + f0);
                    if (jj < cnt) {
                        ac0 += bfpair(va.x); ac1 += bfpair(va.y);
                        ac2 += bfpair(va.z); ac3 += bfpair(va.w);
                    }
                }
            }
            float acc[8] = {ac0.x, ac0.y, ac1.x, ac1.y, ac2.x, ac2.y, ac3.x, ac3.y};
            #pragma unroll
            for (int k = 0; k < 8; ++k) {
                acc[k] += __shfl_xor(acc[k], 8);
                acc[k] += __shfl_xor(acc[k], 16);
                acc[k] += __shfl_xor(acc[k], 32);
            }
            float deg = (float)(e1 - e0);
            uint4 sb = *(const uint4*)(hin + (size_t)node * 64 + f0);
            float self[8] = {bflo(sb.x), bfhi(sb.x), bflo(sb.y), bfhi(sb.y),
                             bflo(sb.z), bfhi(sb.z), bflo(sb.w), bfhi(sb.w)};
            if (grp == 0) {
                u32 pk[4];
                #pragma unroll
                for (int k = 0; k < 4; ++k) {
                    float oa = sc[2 * k] * (acc[2 * k] + epsv * self[2 * k]) +
                               (deg + epsv) * sh[2 * k];
                    float ob = sc[2 * k + 1] * (acc[2 * k + 1] + epsv * self[2 * k + 1]) +
                               (deg + epsv) * sh[2 * k + 1];
                    pk[k] = (u32)f2bf(oa) | ((u32)f2bf(ob) << 16);
                }
                *(uint4*)arow = make_uint4(pk[0], pk[1], pk[2], pk[3]);
            }
        } else if (grp == 0) {
            *(uint4*)arow = make_uint4(0, 0, 0, 0);
        }
    }
    // no barrier: phase B reads only this wave's Ain tile (in-order DS per wave)

    // ---- phase B: MFMA MLP on the wave's 16-row tile (R10 k_mlp, w=0) ----
    const u16* Wt2 = Wt + 4608;
    int m = lane & 15;
    int q = lane >> 4;

    bf16x8 a0 = *(const bf16x8*)(&Ain[wid][m * 72 + q * 8]);
    bf16x8 a1 = *(const bf16x8*)(&Ain[wid][m * 72 + 32 + q * 8]);
    f32x4 acc[4];
    #pragma unroll
    for (int c = 0; c < 4; ++c) {
        acc[c] = (f32x4){0.f, 0.f, 0.f, 0.f};
        bf16x8 bA = *(const bf16x8*)(Wt + (c * 16 + m) * 72 + q * 8);
        bf16x8 bB = *(const bf16x8*)(Wt + (c * 16 + m) * 72 + 32 + q * 8);
        acc[c] = __builtin_amdgcn_mfma_f32_16x16x32_bf16(a0, bA, acc[c], 0, 0, 0);
        acc[c] = __builtin_amdgcn_mfma_f32_16x16x32_bf16(a1, bB, acc[c], 0, 0, 0);
    }
    #pragma unroll
    for (int c = 0; c < 4; ++c) {
        int col = c * 16 + m;
        float bb = b1[col];
        #pragma unroll
        for (int r = 0; r < 4; ++r)
            Hs[wid][(q * 4 + r) * 72 + col] = f2bf(fmaxf(acc[c][r] + bb, 0.f));
    }
    bf16x8 h0 = *(const bf16x8*)(&Hs[wid][m * 72 + q * 8]);
    bf16x8 h1 = *(const bf16x8*)(&Hs[wid][m * 72 + 32 + q * 8]);
    f32x4 acc2[4];
    #pragma unroll
    for (int c = 0; c < 4; ++c) {
        acc2[c] = (f32x4){0.f, 0.f, 0.f, 0.f};
        bf16x8 bA = *(const bf16x8*)(Wt2 + (c * 16 + m) * 72 + q * 8);
        bf16x8 bB = *(const bf16x8*)(Wt2 + (c * 16 + m) * 72 + 32 + q * 8);
        acc2[c] = __builtin_amdgcn_mfma_f32_16x16x32_bf16(h0, bA, acc2[c], 0, 0, 0);
        acc2[c] = __builtin_amdgcn_mfma_f32_16x16x32_bf16(h1, bB, acc2[c], 0, 0, 0);
    }
    size_t prow = ((size_t)blockIdx.x * 2 + wid) * 128;
    #pragma unroll
    for (int c = 0; c < 4; ++c) {
        int col = c * 16 + m;
        float bb = b2[col];
        float psum = 0.f, psq = 0.f;
        #pragma unroll
        for (int r = 0; r < 4; ++r) {
            int rg = r0 + q * 4 + r;
            if (rg < N_NODES) {
                float o = fmaxf(acc2[c][r] + bb, 0.f);
                C[(size_t)rg * 64 + col] = f2bf(o);
                psum += o;
                psq += o * o;
            }
        }
        psum += __shfl_xor(psum, 16);
        psum += __shfl_xor(psum, 32);
        psq += __shfl_xor(psq, 16);
        psq += __shfl_xor(psq, 32);
        if (q == 0) {
            partials[prow + col] = psum;
            partials[prow + 64 + col] = psq;
        }
    }
}

// ---------------- pooling + FC + log_softmax ----------------
__global__ void k_pool(const u16* __restrict__ h, const float* __restrict__ ss,
                       const int* __restrict__ gstart, const float* __restrict__ wfc,
                       const float* __restrict__ bfc, float* __restrict__ out) {
    __shared__ float smean[2][128];
    __shared__ float smax[2][128];
    __shared__ float lg[2][8];
    int tid = threadIdx.x;
    int lane = tid & 63;
    int w = tid >> 6;
    int gi = w >> 1;
    int part = w & 1;
    int gr = blockIdx.x * 2 + gi;
    int half = lane >> 5;
    int li = lane & 31;
    int f0 = 2 * li;
    float sc0 = ss[f0], sc1 = ss[f0 + 1];
    float sh0 = ss[64 + f0], sh1 = ss[64 + f0 + 1];
    int s0n = gstart[gr], s1n = gstart[gr + 1];
    int cnt = s1n - s0n;
    int mid = s0n + (cnt >> 1);
    int a = part ? mid : s0n;
    int b = part ? s1n : mid;
    float sum0 = 0.f, sum1 = 0.f, mx0 = -3.4e38f, mx1 = -3.4e38f;
    for (int n = a + half; n < b; n += 2) {
        u32 bits = *(const u32*)(h + (size_t)n * 64 + f0);
        float x0 = fmaf(bflo(bits), sc0, sh0);
        float x1 = fmaf(bfhi(bits), sc1, sh1);
        sum0 += x0; sum1 += x1;
        mx0 = fmaxf(mx0, x0); mx1 = fmaxf(mx1, x1);
    }
    sum0 += __shfl_xor(sum0, 32);
    sum1 += __shfl_xor(sum1, 32);
    mx0 = fmaxf(mx0, __shfl_xor(mx0, 32));
    mx1 = fmaxf(mx1, __shfl_xor(mx1, 32));
    if (half == 0 && part == 0) {
        smean[gi][f0] = sum0; smean[gi][f0 + 1] = sum1;
        smax[gi][f0] = mx0;   smax[gi][f0 + 1] = mx1;
    }
    __syncthreads();
    if (half == 0 && part == 1) {
        float m0 = fmaxf(smax[gi][f0], mx0), m1 = fmaxf(smax[gi][f0 + 1], mx1);
        float t0 = smean[gi][f0] + sum0, t1 = smean[gi][f0 + 1] + sum1;
        float fc = fmaxf((float)cnt, 1.f);
        smean[gi][f0] = t0 / fc;
        smean[gi][f0 + 1] = t1 / fc;
        smax[gi][f0] = (cnt > 0) ? m0 : 0.f;
        smax[gi][f0 + 1] = (cnt > 0) ? m1 : 0.f;
    }
    __syncthreads();
    if (part == 0 && lane < NCLASS) {
        float acc = bfc[lane];
        for (int j = 0; j < 64; ++j) acc = fmaf(smean[gi][j], wfc[j * NCLASS + lane], acc);
        for (int j = 0; j < 64; ++j) acc = fmaf(smax[gi][j], wfc[(64 + j) * NCLASS + lane], acc);
        lg[gi][lane] = acc;
    }
    __syncthreads();
    if (part == 0 && lane < NCLASS) {
        float mm = -3.4e38f;
        for (int c = 0; c < NCLASS; ++c) mm = fmaxf(mm, lg[gi][c]);
        float se = 0.f;
        for (int c = 0; c < NCLASS; ++c) se += expf(lg[gi][c] - mm);
        out[gr * NCLASS + lane] = lg[gi][lane] - mm - logf(se);
    }
}

// ---------------- launch ----------------

extern "C" void kernel_launch(void* const* d_in, const int* in_sizes, int n_in,
                              void* d_out, int out_size, void* d_ws, size_t ws_size,
                              hipStream_t stream) {
    const float* x = (const float*)d_in[0];
    const int* ei = (const int*)d_in[1];
    const int* batch = (const int*)d_in[2];
    const int* esrc_in = ei;
    const int* edst_in = ei + N_EDGES;

    const float* ba[4] = {(const float*)d_in[4], (const float*)d_in[8],
                          (const float*)d_in[12], (const float*)d_in[12]};
    const float* bb[4] = {(const float*)d_in[6], (const float*)d_in[10],
                          (const float*)d_in[14], (const float*)d_in[14]};
    const float* epsv[4] = {(const float*)d_in[15], (const float*)d_in[18],
                            (const float*)d_in[21], (const float*)d_in[24]};
    const float* gg[4] = {(const float*)d_in[16], (const float*)d_in[19],
                          (const float*)d_in[22], (const float*)d_in[25]};
    const float* bee[4] = {(const float*)d_in[17], (const float*)d_in[20],
                           (const float*)d_in[23], (const float*)d_in[26]};
    const float* wfc = (const float*)d_in[27];
    const float* bfc = (const float*)d_in[28];
    float* out = (float*)d_out;

    char* ws = (char*)d_ws;
    int* pairs = (int*)(ws + 0);               // 12,800,000 (dead after k_bsort)
    u16* bufA = (u16*)(ws + 0);                // alias of pairs (first write: L1)
    int* esrc = (int*)(ws + 12800000);         // 12,800,000
    u16* xb = (u16*)(ws + 25600000);           // 12,800,000
    u16* bufB = (u16*)(ws + 38400000);         // 12,800,000
    int* rowstart = (int*)(ws + 51200000);     // 400,128
    int* blockhist = (int*)(ws + 51600128);    // 612,352 (padded)
    int* colsum = (int*)(ws + 52212480);       // 2,048
    int* gstart = (int*)(ws + 52214528);       // 2,560
    float* partials = (float*)(ws + 52217088); // 6250*128*4 = 3,200,000 -> 3,200,512
    float* ssbuf = (float*)(ws + 55417600);    // 2,560
    u16* Wtg = (u16*)(ws + 55420160);          // 55,296
    // total: 55,475,456 bytes; no memsets needed

    k_setup<<<CAST_B + 97 + EB + NBLK_NODE, 256, 0, stream>>>(
        x, xb, (const float*)d_in[3], (const float*)d_in[5], (const float*)d_in[7],
        (const float*)d_in[9], (const float*)d_in[11], (const float*)d_in[13],
        Wtg, ssbuf, edst_in, batch, blockhist, gstart, rowstart);
    k_scan_cols<<<NBUCK, 512, 0, stream>>>(blockhist, colsum);
    k_bscatter<<<EB, 512, 0, stream>>>(esrc_in, edst_in, colsum, blockhist, pairs);
    k_bsort<<<NBUCK, 512, 0, stream>>>(pairs, colsum, rowstart, esrc);

    // ping-pong: L0 xb->B, L1 B->A, L2 A->B, L3 B->A; pool reads A
    const u16* hb[4] = {xb, bufB, bufA, bufB};
    u16* cb[4] = {bufB, bufA, bufB, bufA};
    for (int L = 0; L < 4; ++L) {
        const u16* wt = Wtg + (size_t)((L < 2) ? L : 2) * 9216;
        k_fused<<<FUSG, 128, 0, stream>>>(hb[L], ssbuf + L * 128, epsv[L], rowstart,
                                          esrc, wt, ba[L], bb[L], cb[L], partials);
        k_bn<<<64, 256, 0, stream>>>(partials, gg[L], bee[L], ssbuf + (L + 1) * 128);
    }

    k_pool<<<NGRAPH / 2, 256, 0, stream>>>(bufA, ssbuf + 4 * 128, gstart, wfc, bfc, out);
}